// Round 6
// baseline (415.550 us; speedup 1.0000x reference)
//
#include <hip/hip_runtime.h>
#include <cstdint>

// Problem constants (fixed shapes)
#define E_DIM   576
#define HEADS   18
#define NPTS    12
#define DDEPTH  5
#define HDIM    32
#define BSZ     2
#define GH      64
#define GW      80
#define NQ      (GH*GW)       // 5120
#define NTOK    (NQ*DDEPTH)   // 25600
#define MIXW    864           // 648 offsets + 216 attn logits

typedef __attribute__((ext_vector_type(8))) short short8;
typedef __attribute__((ext_vector_type(4))) float f32x4;

__device__ __forceinline__ float b2f_lo(uint32_t u) {
    union { uint32_t u; float f; } v; v.u = u << 16; return v.f;
}
__device__ __forceinline__ float b2f_hi(uint32_t u) {
    union { uint32_t u; float f; } v; v.u = u & 0xffff0000u; return v.f;
}
__device__ __forceinline__ ushort f2b(float f) {
    union { float f; uint32_t u; } v; v.f = f;
    return (ushort)((v.u + 0x7fffu + ((v.u >> 16) & 1u)) >> 16);
}
// RNE-pack two fp32 -> packed bf16x2 (low = a, high = b)
__device__ __forceinline__ uint32_t pkbf(float a, float b) {
    uint32_t ua = __float_as_uint(a), ub = __float_as_uint(b);
    ua = ua + 0x7fffu + ((ua >> 16) & 1u);
    ub = ub + 0x7fffu + ((ub >> 16) & 1u);
    return (ua >> 16) | (ub & 0xffff0000u);
}

// ---------------------------------------------------------------------------
// all weight prep in one launch
__global__ void prep_weights(const float* __restrict__ W_v, const float* __restrict__ W_out,
                             const float* __restrict__ W_off, const float* __restrict__ W_attn,
                             const float* __restrict__ b_off, const float* __restrict__ b_attn,
                             ushort* __restrict__ wt_v, ushort* __restrict__ wt_out,
                             ushort* __restrict__ wt_mix, float* __restrict__ bias_mix) {
    int idx = blockIdx.x * blockDim.x + threadIdx.x;
    if (idx < 864) bias_mix[idx] = (idx < 648) ? b_off[idx] : b_attn[idx - 648];
    if (idx < 331776) {
        int n = idx / E_DIM, k = idx - n * E_DIM;
        wt_v[idx] = f2b(W_v[(size_t)k * E_DIM + n]);
    } else if (idx < 663552) {
        int j = idx - 331776;
        int n = j / E_DIM, k = j - n * E_DIM;
        wt_out[j] = f2b(W_out[(size_t)k * E_DIM + n]);
    } else if (idx < 1161216) {
        int j = idx - 663552;
        int n = j / E_DIM, k = j - n * E_DIM;
        float v = (n < 648) ? W_off[(size_t)k * 648 + n] : W_attn[(size_t)k * 216 + (n - 648)];
        wt_mix[j] = f2b(v);
    }
}

// ---------------------------------------------------------------------------
// MFMA GEMM with XOR-swizzled LDS: tile 128x96, BK=32, 256 threads = 4 waves.
// Logical tile element (row, k) with chunk kc = k/8; 2-row block t = row/2,
// u = (row&1)*4 + kc; physical 16B-chunk index P = t*8 + (u ^ (t&7)).
// Fragment ds_read_b128 then hits each bank-quad exactly 2x per 16-lane
// phase (2-way aliasing is free on gfx950).
// AMODE: 0 = A is bf16, async global_load_lds staging (swizzle via source perm)
//        1 = A is fp32, register staging: load->RNE pack->ds_write_b128
//        2 = like 1 but A = A1 + A2 (two fp32 streams added)
#define TM 128
#define TN 96
#define BK 32

__device__ __forceinline__ void async_cp16(const ushort* gsrc, ushort* ldst) {
    __builtin_amdgcn_global_load_lds(
        (const __attribute__((address_space(1))) void*)gsrc,
        (__attribute__((address_space(3))) void*)ldst, 16, 0, 0);
}

// invert swizzle: physical chunk P -> logical (row, kc)
__device__ __forceinline__ void dec_swz(int P, int& row, int& kc) {
    const int t = P >> 3;
    const int u = (P & 7) ^ (t & 7);
    row = (t << 1) | (u >> 2);
    kc  = u & 3;
}
// forward swizzle for fragment reads: (row, kc) -> ushort offset
__device__ __forceinline__ int swz_off(int row, int kc) {
    const int t = row >> 1;
    const int u = ((row & 1) << 2) | kc;
    return t * 64 + ((u ^ (t & 7)) << 3);
}

template <int AMODE, typename OutT>
__global__ __launch_bounds__(256) void
gemm_mfma(const void* __restrict__ Ap, const float* __restrict__ A2,
          const ushort* __restrict__ Bt, const float* __restrict__ bias,
          OutT* __restrict__ C, int M, int N, int K, int ldc) {
    __shared__ __align__(16) ushort Asb[TM * BK];   // 8192 B, swizzled
    __shared__ __align__(16) ushort Bsb[TN * BK];   // 6144 B, swizzled
    const int tid  = threadIdx.x;
    const int wave = tid >> 6;
    const int lane = tid & 63;
    const int m16  = lane & 15;
    const int quad = lane >> 4;
    const int row0 = blockIdx.x * TM;
    const int n0   = blockIdx.y * TN;

    const f32x4 zero = {0.f, 0.f, 0.f, 0.f};
    f32x4 acc[2][6];
    #pragma unroll
    for (int rt = 0; rt < 2; ++rt)
        #pragma unroll
        for (int ct = 0; ct < 6; ++ct) acc[rt][ct] = zero;

    // --- per-lane staging sources (swizzle-permuted) ---
    // B: async, chunks P = issue*64 + lane; this wave handles issues {wave, wave+4<6}
    int bn0, bkc0, bn1, bkc1;
    dec_swz(wave * 64 + lane, bn0, bkc0);
    dec_swz((wave + 4) * 64 + lane, bn1, bkc1);
    const ushort* gB0 = Bt + (size_t)(n0 + bn0) * K + bkc0 * 8;
    const ushort* gB1 = Bt + (size_t)(n0 + bn1) * K + bkc1 * 8;
    ushort* dB0 = Bsb + wave * 512;
    ushort* dB1 = Bsb + (wave + 4) * 512;

    // A staging descriptors
    const ushort* gA0 = nullptr; const ushort* gA1 = nullptr;     // AMODE 0
    ushort* dA0 = nullptr; ushort* dA1 = nullptr;
    const float* fA0 = nullptr; const float* fA1 = nullptr;       // AMODE 1/2
    const float* fB0a = nullptr; const float* fB1a = nullptr;     // AMODE 2 second stream
    uint32_t* wA0 = nullptr; uint32_t* wA1 = nullptr;
    if constexpr (AMODE == 0) {
        const ushort* A = (const ushort*)Ap;
        int m, kc;
        dec_swz(wave * 64 + lane, m, kc);
        gA0 = A + (size_t)(row0 + m) * K + kc * 8;
        dA0 = Asb + wave * 512;
        dec_swz((wave + 4) * 64 + lane, m, kc);
        gA1 = A + (size_t)(row0 + m) * K + kc * 8;
        dA1 = Asb + (wave + 4) * 512;
    } else {
        const float* A = (const float*)Ap;
        int m, kc;
        dec_swz(tid, m, kc);
        fA0 = A + (size_t)(row0 + m) * K + kc * 8;
        if constexpr (AMODE == 2) fB0a = A2 + (size_t)(row0 + m) * K + kc * 8;
        wA0 = (uint32_t*)(Asb + tid * 8);
        dec_swz(tid + 256, m, kc);
        fA1 = A + (size_t)(row0 + m) * K + kc * 8;
        if constexpr (AMODE == 2) fB1a = A2 + (size_t)(row0 + m) * K + kc * 8;
        wA1 = (uint32_t*)(Asb + (tid + 256) * 8);
    }

    // fragment read offsets (k-independent, swizzled)
    int aoff[2], boff[6];
    #pragma unroll
    for (int rt = 0; rt < 2; ++rt)
        aoff[rt] = swz_off(wave * 32 + rt * 16 + m16, quad);
    #pragma unroll
    for (int ct = 0; ct < 6; ++ct)
        boff[ct] = swz_off(ct * 16 + m16, quad);

    for (int k0 = 0; k0 < K; k0 += BK) {
        // B: async staging
        async_cp16(gB0 + k0, dB0);
        if (wave < 2) async_cp16(gB1 + k0, dB1);
        // A: staging
        if constexpr (AMODE == 0) {
            async_cp16(gA0 + k0, dA0);
            async_cp16(gA1 + k0, dA1);
        } else {
            float4 x0 = *reinterpret_cast<const float4*>(fA0 + k0);
            float4 x1 = *reinterpret_cast<const float4*>(fA0 + k0 + 4);
            float4 y0 = *reinterpret_cast<const float4*>(fA1 + k0);
            float4 y1 = *reinterpret_cast<const float4*>(fA1 + k0 + 4);
            if constexpr (AMODE == 2) {
                const float4 p0 = *reinterpret_cast<const float4*>(fB0a + k0);
                const float4 p1 = *reinterpret_cast<const float4*>(fB0a + k0 + 4);
                const float4 q0 = *reinterpret_cast<const float4*>(fB1a + k0);
                const float4 q1 = *reinterpret_cast<const float4*>(fB1a + k0 + 4);
                x0.x += p0.x; x0.y += p0.y; x0.z += p0.z; x0.w += p0.w;
                x1.x += p1.x; x1.y += p1.y; x1.z += p1.z; x1.w += p1.w;
                y0.x += q0.x; y0.y += q0.y; y0.z += q0.z; y0.w += q0.w;
                y1.x += q1.x; y1.y += q1.y; y1.z += q1.z; y1.w += q1.w;
            }
            uint4 o;
            o.x = pkbf(x0.x, x0.y); o.y = pkbf(x0.z, x0.w);
            o.z = pkbf(x1.x, x1.y); o.w = pkbf(x1.z, x1.w);
            *reinterpret_cast<uint4*>(wA0) = o;
            o.x = pkbf(y0.x, y0.y); o.y = pkbf(y0.z, y0.w);
            o.z = pkbf(y1.x, y1.y); o.w = pkbf(y1.z, y1.w);
            *reinterpret_cast<uint4*>(wA1) = o;
        }
        __syncthreads();   // drains vmcnt (async) + lgkmcnt (ds_write)

        short8 afrag[2], bfrag[6];
        #pragma unroll
        for (int rt = 0; rt < 2; ++rt)
            afrag[rt] = *reinterpret_cast<const short8*>(Asb + aoff[rt]);
        #pragma unroll
        for (int ct = 0; ct < 6; ++ct)
            bfrag[ct] = *reinterpret_cast<const short8*>(Bsb + boff[ct]);

        #pragma unroll
        for (int rt = 0; rt < 2; ++rt)
            #pragma unroll
            for (int ct = 0; ct < 6; ++ct)
                acc[rt][ct] = __builtin_amdgcn_mfma_f32_16x16x32_bf16(
                    afrag[rt], bfrag[ct], acc[rt][ct], 0, 0, 0);

        __syncthreads();   // protect LDS before next-iter overwrite
    }

    // epilogue: C/D layout col=lane&15, row=quad*4+reg
    #pragma unroll
    for (int ct = 0; ct < 6; ++ct) {
        const int col = n0 + ct * 16 + m16;
        const float bcol = bias[col];
        #pragma unroll
        for (int rt = 0; rt < 2; ++rt) {
            #pragma unroll
            for (int r = 0; r < 4; ++r) {
                const int row = row0 + wave * 32 + rt * 16 + quad * 4 + r;
                const float val = acc[rt][ct][r] + bcol;
                if constexpr (__is_same(OutT, float)) {
                    C[(size_t)row * ldc + col] = val;
                } else {
                    C[(size_t)row * ldc + col] = f2b(val);
                }
            }
        }
    }
}

// ---------------------------------------------------------------------------
// Deformable 3D trilinear attention — register/shuffle version, head-major.
__global__ void __launch_bounds__(256, 8)
deform_kernel(const ushort* __restrict__ vbuf,
              const float* __restrict__ mix,
              ushort* __restrict__ aout) {
    const int gl   = threadIdx.x >> 4;   // subgroup in block
    const int l    = threadIdx.x & 15;
    const int head = blockIdx.x / 640;                   // block-uniform
    const int bq   = (blockIdx.x % 640) * 16 + gl;       // b*NQ + q
    const int q    = bq % NQ;
    const int b    = bq / NQ;
    const int qx   = q % GW;
    const int qy   = q / GW;

    const float* mrow = mix + (size_t)bq * MIXW;

    // softmax (lanes 0..11 hold one logit each)
    float lg = (l < NPTS) ? mrow[648 + head * NPTS + l] : -1e30f;
    float mx = lg;
    #pragma unroll
    for (int mk = 1; mk < 16; mk <<= 1) mx = fmaxf(mx, __shfl_xor(mx, mk, 16));
    float e = (l < NPTS) ? __expf(lg - mx) : 0.f;
    float s = e;
    #pragma unroll
    for (int mk = 1; mk < 16; mk <<= 1) s += __shfl_xor(s, mk, 16);

    // corner geometry for point l (lanes 0..11), all in regs
    float    cw[8];
    uint32_t coff[8];
    uint32_t mask = 0;
    {
        const float ap = e / s;
        const int pl = (l < NPTS) ? l : 0;
        const int ob = (head * NPTS + pl) * 3;
        const float ox = mrow[ob + 0];
        const float oy = mrow[ob + 1];
        const float oz = mrow[ob + 2];
        const float x = (float)qx + ox;          // = loc_x*W - 0.5
        const float y = (float)qy + oy;
        const float z = oz * (5.0f / 3.0f) - 0.5f;
        const float x0f = floorf(x), y0f = floorf(y), z0f = floorf(z);
        const int x0 = (int)x0f, y0 = (int)y0f, z0 = (int)z0f;
        const float fx = x - x0f, fy = y - y0f, fz = z - z0f;

        #pragma unroll
        for (int dz = 0; dz < 2; ++dz) {
            const int zi = z0 + dz;
            const bool zv = (zi >= 0) & (zi < DDEPTH);
            const int zc = min(max(zi, 0), DDEPTH - 1);
            const float wz = dz ? fz : 1.f - fz;
            #pragma unroll
            for (int dy = 0; dy < 2; ++dy) {
                const int yi = y0 + dy;
                const bool yv = (yi >= 0) & (yi < GH);
                const int yc = min(max(yi, 0), GH - 1);
                const float wy = dy ? fy : 1.f - fy;
                #pragma unroll
                for (int dx = 0; dx < 2; ++dx) {
                    const int xi = x0 + dx;
                    const bool xv = (xi >= 0) & (xi < GW);
                    const int xc = min(max(xi, 0), GW - 1);
                    const float wx = dx ? fx : 1.f - fx;
                    const int i = dz * 4 + dy * 2 + dx;
                    const bool valid = zv & yv & xv & (l < NPTS);
                    cw[i]   = ap * wz * wy * wx;
                    coff[i] = (uint32_t)((zc * GH + yc) * GW + xc) * (E_DIM / 2);
                    mask |= (valid ? (1u << i) : 0u);
                }
            }
        }
    }

    // gather (all 16 lanes; lane = channel pair)
    const uint32_t* vb = reinterpret_cast<const uint32_t*>(vbuf)
                         + (size_t)b * NTOK * (E_DIM / 2) + head * (HDIM / 2) + l;
    float o0 = 0.f, o1 = 0.f;
    #pragma unroll
    for (int p = 0; p < NPTS; ++p) {
        const uint32_t msk = (uint32_t)__shfl((int)mask, p, 16);
        if (msk == 0) continue;   // near wave-uniform skip
        #pragma unroll
        for (int i = 0; i < 8; ++i) {
            if (msk & (1u << i)) {
                const float    w   = __shfl(cw[i], p, 16);
                const uint32_t off = (uint32_t)__shfl((int)coff[i], p, 16);
                const uint32_t pair = vb[off];
                o0 += w * b2f_lo(pair);
                o1 += w * b2f_hi(pair);
            }
        }
    }
    const uint32_t packed = (uint32_t)f2b(o0) | ((uint32_t)f2b(o1) << 16);
    reinterpret_cast<uint32_t*>(aout)[(size_t)bq * (E_DIM / 2) + head * (HDIM / 2) + l] = packed;
}

// ---------------------------------------------------------------------------
extern "C" void kernel_launch(void* const* d_in, const int* in_sizes, int n_in,
                              void* d_out, int out_size, void* d_ws, size_t ws_size,
                              hipStream_t stream) {
    const float* query     = (const float*)d_in[0];
    const float* value     = (const float*)d_in[1];
    const float* query_pos = (const float*)d_in[2];
    const float* W_off     = (const float*)d_in[3];
    const float* b_off     = (const float*)d_in[4];
    const float* W_attn    = (const float*)d_in[5];
    const float* b_attn    = (const float*)d_in[6];
    const float* W_v       = (const float*)d_in[7];
    const float* b_v       = (const float*)d_in[8];
    const float* W_out     = (const float*)d_in[9];
    const float* b_out     = (const float*)d_in[10];
    float* out = (float*)d_out;

    char* ws = (char*)d_ws;
    ushort* vbuf     = (ushort*)(ws);                  // 51200*576*2 = 58,982,400
    ushort* aout     = (ushort*)(ws + 58982400);       // 10240*576*2 = 11,796,480
    float*  mixb     = (float*) (ws + 70778880);       // 10240*864*4 = 35,389,440
    ushort* wt_v     = (ushort*)(ws + 106168320);      // 663,552
    ushort* wt_out   = (ushort*)(ws + 106831872);      // 663,552
    ushort* wt_mix   = (ushort*)(ws + 107495424);      // 995,328
    float*  bias_mix = (float*) (ws + 108490752);      // 3,456

    prep_weights<<<(1161216 + 255) / 256, 256, 0, stream>>>(
        W_v, W_out, W_off, W_attn, b_off, b_attn, wt_v, wt_out, wt_mix, bias_mix);

    // mix = (query + query_pos) @ [W_off|W_attn] + bias : (10240 x 864), fp32 out
    gemm_mfma<2, float><<<dim3(10240 / TM, MIXW / TN), 256, 0, stream>>>(
        query, query_pos, wt_mix, bias_mix, mixb, BSZ * NQ, MIXW, E_DIM, MIXW);

    // v = value @ W_v + b_v : (51200 x 576), fp32 A staged+cast in-kernel, bf16 out
    gemm_mfma<1, ushort><<<dim3(51200 / TM, E_DIM / TN), 256, 0, stream>>>(
        value, nullptr, wt_v, b_v, vbuf, BSZ * NTOK, E_DIM, E_DIM, E_DIM);

    // deformable gather + softmax-weighted sum -> aout (bf16), head-major grid
    deform_kernel<<<HEADS * 640, 256, 0, stream>>>(vbuf, mixb, aout);

    // out = aout @ W_out + b_out : (10240 x 576), fp32 to d_out
    gemm_mfma<0, float><<<dim3(10240 / TM, E_DIM / TN), 256, 0, stream>>>(
        aout, nullptr, wt_out, b_out, out, BSZ * NQ, E_DIM, E_DIM, E_DIM);
}

// Round 7
// 414.949 us; speedup vs baseline: 1.0014x; 1.0014x over previous
//
#include <hip/hip_runtime.h>
#include <cstdint>

// Problem constants (fixed shapes)
#define E_DIM   576
#define HEADS   18
#define NPTS    12
#define DDEPTH  5
#define HDIM    32
#define BSZ     2
#define GH      64
#define GW      80
#define NQ      (GH*GW)       // 5120
#define NTOK    (NQ*DDEPTH)   // 25600
#define MIXW    864           // 648 offsets + 216 attn logits

typedef __attribute__((ext_vector_type(8))) short short8;
typedef __attribute__((ext_vector_type(4))) float f32x4;

__device__ __forceinline__ float b2f_lo(uint32_t u) {
    union { uint32_t u; float f; } v; v.u = u << 16; return v.f;
}
__device__ __forceinline__ float b2f_hi(uint32_t u) {
    union { uint32_t u; float f; } v; v.u = u & 0xffff0000u; return v.f;
}
__device__ __forceinline__ ushort f2b(float f) {
    union { float f; uint32_t u; } v; v.f = f;
    return (ushort)((v.u + 0x7fffu + ((v.u >> 16) & 1u)) >> 16);
}
// RNE-pack two fp32 -> packed bf16x2 (low = a, high = b)
__device__ __forceinline__ uint32_t pkbf(float a, float b) {
    uint32_t ua = __float_as_uint(a), ub = __float_as_uint(b);
    ua = ua + 0x7fffu + ((ua >> 16) & 1u);
    ub = ub + 0x7fffu + ((ub >> 16) & 1u);
    return (ua >> 16) | (ub & 0xffff0000u);
}

__device__ __forceinline__ void async_cp16(const ushort* gsrc, ushort* ldst) {
    __builtin_amdgcn_global_load_lds(
        (const __attribute__((address_space(1))) void*)gsrc,
        (__attribute__((address_space(3))) void*)ldst, 16, 0, 0);
}

// XOR swizzle over 8-chunk groups (2 rows x 4 chunks of 16B):
// physical chunk P <-> logical (row, kc): t=row/2, u=(row&1)*4+kc, P=t*8+(u^(t&7))
__device__ __forceinline__ void dec_swz(int P, int& row, int& kc) {
    const int t = P >> 3;
    const int u = (P & 7) ^ (t & 7);
    row = (t << 1) | (u >> 2);
    kc  = u & 3;
}
__device__ __forceinline__ int swz_off(int row, int kc) {   // ushort offset
    const int t = row >> 1;
    const int u = ((row & 1) << 2) | kc;
    return t * 64 + ((u ^ (t & 7)) << 3);
}

// ---------------------------------------------------------------------------
// q = query + query_pos, cast to bf16 (packed)
__global__ void cast_add_kernel(const float* __restrict__ a, const float* __restrict__ b,
                                ushort* __restrict__ out, int n4) {
    int i = blockIdx.x * blockDim.x + threadIdx.x;
    if (i >= n4) return;
    const float4 va = reinterpret_cast<const float4*>(a)[i];
    const float4 vb = reinterpret_cast<const float4*>(b)[i];
    uint2 o;
    o.x = pkbf(va.x + vb.x, va.y + vb.y);
    o.y = pkbf(va.z + vb.z, va.w + vb.w);
    reinterpret_cast<uint2*>(out)[i] = o;
}

// all weight prep in one launch
__global__ void prep_weights(const float* __restrict__ W_v, const float* __restrict__ W_out,
                             const float* __restrict__ W_off, const float* __restrict__ W_attn,
                             const float* __restrict__ b_off, const float* __restrict__ b_attn,
                             ushort* __restrict__ wt_v, ushort* __restrict__ wt_out,
                             ushort* __restrict__ wt_mix, float* __restrict__ bias_mix) {
    int idx = blockIdx.x * blockDim.x + threadIdx.x;
    if (idx < 864) bias_mix[idx] = (idx < 648) ? b_off[idx] : b_attn[idx - 648];
    if (idx < 331776) {
        int n = idx / E_DIM, k = idx - n * E_DIM;
        wt_v[idx] = f2b(W_v[(size_t)k * E_DIM + n]);
    } else if (idx < 663552) {
        int j = idx - 331776;
        int n = j / E_DIM, k = j - n * E_DIM;
        wt_out[j] = f2b(W_out[(size_t)k * E_DIM + n]);
    } else if (idx < 1161216) {
        int j = idx - 663552;
        int n = j / E_DIM, k = j - n * E_DIM;
        float v = (n < 648) ? W_off[(size_t)k * 648 + n] : W_attn[(size_t)k * 216 + (n - 648)];
        wt_mix[j] = f2b(v);
    }
}

// ---------------------------------------------------------------------------
// Generic MFMA GEMM (bf16 A, async staging, swizzled LDS): tile 128x96, BK=32.
#define TM 128
#define TN 96
#define BK 32

template <typename OutT>
__global__ __launch_bounds__(256) void
gemm_mfma(const ushort* __restrict__ A, const ushort* __restrict__ Bt,
          const float* __restrict__ bias, OutT* __restrict__ C,
          int M, int N, int K, int ldc) {
    __shared__ __align__(16) ushort Asb[TM * BK];   // 8192 B, swizzled
    __shared__ __align__(16) ushort Bsb[TN * BK];   // 6144 B, swizzled
    const int tid  = threadIdx.x;
    const int wave = tid >> 6;
    const int lane = tid & 63;
    const int m16  = lane & 15;
    const int quad = lane >> 4;
    const int row0 = blockIdx.x * TM;
    const int n0   = blockIdx.y * TN;

    const f32x4 zero = {0.f, 0.f, 0.f, 0.f};
    f32x4 acc[2][6];
    #pragma unroll
    for (int rt = 0; rt < 2; ++rt)
        #pragma unroll
        for (int ct = 0; ct < 6; ++ct) acc[rt][ct] = zero;

    // staging sources, swizzle-permuted (dest lane-contiguous per wave)
    int r, kc;
    dec_swz(wave * 64 + lane, r, kc);
    const ushort* gA0 = A + (size_t)(row0 + r) * K + kc * 8;
    dec_swz((wave + 4) * 64 + lane, r, kc);
    const ushort* gA1 = A + (size_t)(row0 + r) * K + kc * 8;
    ushort* dA0 = Asb + (wave * 64 + lane) * 8;
    ushort* dA1 = Asb + ((wave + 4) * 64 + lane) * 8;

    dec_swz(wave * 64 + lane, r, kc);
    const ushort* gB0 = Bt + (size_t)(n0 + r) * K + kc * 8;
    dec_swz((wave + 4) * 64 + lane, r, kc);
    const ushort* gB1 = Bt + (size_t)(n0 + r) * K + kc * 8;
    ushort* dB0 = Bsb + (wave * 64 + lane) * 8;
    ushort* dB1 = Bsb + ((wave + 4) * 64 + lane) * 8;

    // fragment read offsets (k-independent, swizzled)
    int aoff[2], boff[6];
    #pragma unroll
    for (int rt = 0; rt < 2; ++rt)
        aoff[rt] = swz_off(wave * 32 + rt * 16 + m16, quad);
    #pragma unroll
    for (int ct = 0; ct < 6; ++ct)
        boff[ct] = swz_off(ct * 16 + m16, quad);

    for (int k0 = 0; k0 < K; k0 += BK) {
        async_cp16(gA0 + k0, dA0);
        async_cp16(gA1 + k0, dA1);
        async_cp16(gB0 + k0, dB0);
        if (wave < 2) async_cp16(gB1 + k0, dB1);
        __syncthreads();

        short8 afrag[2], bfrag[6];
        #pragma unroll
        for (int rt = 0; rt < 2; ++rt)
            afrag[rt] = *reinterpret_cast<const short8*>(Asb + aoff[rt]);
        #pragma unroll
        for (int ct = 0; ct < 6; ++ct)
            bfrag[ct] = *reinterpret_cast<const short8*>(Bsb + boff[ct]);

        #pragma unroll
        for (int rt = 0; rt < 2; ++rt)
            #pragma unroll
            for (int ct = 0; ct < 6; ++ct)
                acc[rt][ct] = __builtin_amdgcn_mfma_f32_16x16x32_bf16(
                    afrag[rt], bfrag[ct], acc[rt][ct], 0, 0, 0);

        __syncthreads();
    }

    #pragma unroll
    for (int ct = 0; ct < 6; ++ct) {
        const int col = n0 + ct * 16 + m16;
        const float bcol = bias[col];
        #pragma unroll
        for (int rt = 0; rt < 2; ++rt) {
            #pragma unroll
            for (int rr = 0; rr < 4; ++rr) {
                const int row = row0 + wave * 32 + rt * 16 + quad * 4 + rr;
                const float val = acc[rt][ct][rr] + bcol;
                if constexpr (__is_same(OutT, float)) {
                    C[(size_t)row * ldc + col] = val;
                } else {
                    C[(size_t)row * ldc + col] = f2b(val);
                }
            }
        }
    }
}

// ---------------------------------------------------------------------------
// Value-projection GEMM, persistent over N: block = 32-row strip x all 576 cols.
// A (fp32) strip cast->bf16 into swizzled LDS ONCE; B streamed per K-tile from
// L2 (B total 0.66 MB). Wave w covers cols [w*144, w*144+144) = 9 col-tiles.
#define VTM 32

__global__ __launch_bounds__(256) void
gemm_value(const float* __restrict__ A, const ushort* __restrict__ Bt,
           const float* __restrict__ bias, ushort* __restrict__ C) {
    __shared__ __align__(16) ushort Asb[VTM * E_DIM];   // 36864 B, swizzle: r*72 + (c ^ (r&7))
    __shared__ __align__(16) ushort Bsb[E_DIM * BK];    // 36864 B, swz_off layout
    const int tid  = threadIdx.x;
    const int wave = tid >> 6;
    const int lane = tid & 63;
    const int m16  = lane & 15;
    const int quad = lane >> 4;
    const int row0 = blockIdx.x * VTM;

    // --- stage A strip once: fp32 -> bf16, swizzled (9 chunks/thread) ---
    #pragma unroll
    for (int i = 0; i < 9; ++i) {
        const int ch = tid + i * 256;        // 0..2303
        const int rr = ch / 72, cc = ch - rr * 72;
        const float* src = A + (size_t)(row0 + rr) * E_DIM + cc * 8;
        const float4 x0 = *reinterpret_cast<const float4*>(src);
        const float4 x1 = *reinterpret_cast<const float4*>(src + 4);
        uint4 o;
        o.x = pkbf(x0.x, x0.y); o.y = pkbf(x0.z, x0.w);
        o.z = pkbf(x1.x, x1.y); o.w = pkbf(x1.z, x1.w);
        *reinterpret_cast<uint4*>(Asb + (rr * 72 + (cc ^ (rr & 7))) * 8) = o;
    }

    // --- B staging source offsets (9 issues/thread, kt-invariant parts) ---
    int bsoff[9];
    #pragma unroll
    for (int i = 0; i < 9; ++i) {
        int n, kc;
        dec_swz(i * 256 + tid, n, kc);
        bsoff[i] = n * E_DIM + kc * 8;
    }
    ushort* const bdst = Bsb + tid * 8;      // + i*2048, lane-contiguous per wave

    const f32x4 zero = {0.f, 0.f, 0.f, 0.f};
    f32x4 acc[2][9];
    #pragma unroll
    for (int rt = 0; rt < 2; ++rt)
        #pragma unroll
        for (int ct = 0; ct < 9; ++ct) acc[rt][ct] = zero;

    // fragment offsets
    int boff[9];
    #pragma unroll
    for (int ct = 0; ct < 9; ++ct)
        boff[ct] = swz_off(wave * 144 + ct * 16 + m16, quad);
    const int ar0 = (m16) * 72;          // row rt=0: m16
    const int ar1 = (m16 + 16) * 72;     // row rt=1: m16+16
    const int ax0 = m16 & 7;
    const int ax1 = (m16 + 16) & 7;

    for (int kt = 0; kt < E_DIM / BK; ++kt) {
        #pragma unroll
        for (int i = 0; i < 9; ++i)
            async_cp16(Bt + bsoff[i] + kt * BK, bdst + i * 2048);
        __syncthreads();

        const int c = kt * 4 + quad;     // global 8-k chunk
        short8 afrag[2], bfrag[9];
        afrag[0] = *reinterpret_cast<const short8*>(Asb + (ar0 + (c ^ ax0)) * 8);
        afrag[1] = *reinterpret_cast<const short8*>(Asb + (ar1 + (c ^ ax1)) * 8);
        #pragma unroll
        for (int ct = 0; ct < 9; ++ct)
            bfrag[ct] = *reinterpret_cast<const short8*>(Bsb + boff[ct]);

        #pragma unroll
        for (int rt = 0; rt < 2; ++rt)
            #pragma unroll
            for (int ct = 0; ct < 9; ++ct)
                acc[rt][ct] = __builtin_amdgcn_mfma_f32_16x16x32_bf16(
                    afrag[rt], bfrag[ct], acc[rt][ct], 0, 0, 0);

        __syncthreads();
    }

    // epilogue
    #pragma unroll
    for (int ct = 0; ct < 9; ++ct) {
        const int col = wave * 144 + ct * 16 + m16;
        const float bcol = bias[col];
        #pragma unroll
        for (int rt = 0; rt < 2; ++rt) {
            #pragma unroll
            for (int rr = 0; rr < 4; ++rr) {
                const int row = row0 + rt * 16 + quad * 4 + rr;
                C[(size_t)row * E_DIM + col] = f2b(acc[rt][ct][rr] + bcol);
            }
        }
    }
}

// ---------------------------------------------------------------------------
// Deformable 3D trilinear attention — register/shuffle version, head-major.
__global__ void __launch_bounds__(256, 8)
deform_kernel(const ushort* __restrict__ vbuf,
              const float* __restrict__ mix,
              ushort* __restrict__ aout) {
    const int gl   = threadIdx.x >> 4;   // subgroup in block
    const int l    = threadIdx.x & 15;
    const int head = blockIdx.x / 640;                   // block-uniform
    const int bq   = (blockIdx.x % 640) * 16 + gl;       // b*NQ + q
    const int q    = bq % NQ;
    const int b    = bq / NQ;
    const int qx   = q % GW;
    const int qy   = q / GW;

    const float* mrow = mix + (size_t)bq * MIXW;

    // softmax (lanes 0..11 hold one logit each)
    float lg = (l < NPTS) ? mrow[648 + head * NPTS + l] : -1e30f;
    float mx = lg;
    #pragma unroll
    for (int mk = 1; mk < 16; mk <<= 1) mx = fmaxf(mx, __shfl_xor(mx, mk, 16));
    float e = (l < NPTS) ? __expf(lg - mx) : 0.f;
    float s = e;
    #pragma unroll
    for (int mk = 1; mk < 16; mk <<= 1) s += __shfl_xor(s, mk, 16);

    // corner geometry for point l (lanes 0..11), all in regs
    float    cw[8];
    uint32_t coff[8];
    uint32_t mask = 0;
    {
        const float ap = e / s;
        const int pl = (l < NPTS) ? l : 0;
        const int ob = (head * NPTS + pl) * 3;
        const float ox = mrow[ob + 0];
        const float oy = mrow[ob + 1];
        const float oz = mrow[ob + 2];
        const float x = (float)qx + ox;          // = loc_x*W - 0.5
        const float y = (float)qy + oy;
        const float z = oz * (5.0f / 3.0f) - 0.5f;
        const float x0f = floorf(x), y0f = floorf(y), z0f = floorf(z);
        const int x0 = (int)x0f, y0 = (int)y0f, z0 = (int)z0f;
        const float fx = x - x0f, fy = y - y0f, fz = z - z0f;

        #pragma unroll
        for (int dz = 0; dz < 2; ++dz) {
            const int zi = z0 + dz;
            const bool zv = (zi >= 0) & (zi < DDEPTH);
            const int zc = min(max(zi, 0), DDEPTH - 1);
            const float wz = dz ? fz : 1.f - fz;
            #pragma unroll
            for (int dy = 0; dy < 2; ++dy) {
                const int yi = y0 + dy;
                const bool yv = (yi >= 0) & (yi < GH);
                const int yc = min(max(yi, 0), GH - 1);
                const float wy = dy ? fy : 1.f - fy;
                #pragma unroll
                for (int dx = 0; dx < 2; ++dx) {
                    const int xi = x0 + dx;
                    const bool xv = (xi >= 0) & (xi < GW);
                    const int xc = min(max(xi, 0), GW - 1);
                    const float wx = dx ? fx : 1.f - fx;
                    const int i = dz * 4 + dy * 2 + dx;
                    const bool valid = zv & yv & xv & (l < NPTS);
                    cw[i]   = ap * wz * wy * wx;
                    coff[i] = (uint32_t)((zc * GH + yc) * GW + xc) * (E_DIM / 2);
                    mask |= (valid ? (1u << i) : 0u);
                }
            }
        }
    }

    // gather (all 16 lanes; lane = channel pair)
    const uint32_t* vb = reinterpret_cast<const uint32_t*>(vbuf)
                         + (size_t)b * NTOK * (E_DIM / 2) + head * (HDIM / 2) + l;
    float o0 = 0.f, o1 = 0.f;
    #pragma unroll
    for (int p = 0; p < NPTS; ++p) {
        const uint32_t msk = (uint32_t)__shfl((int)mask, p, 16);
        if (msk == 0) continue;   // near wave-uniform skip
        #pragma unroll
        for (int i = 0; i < 8; ++i) {
            if (msk & (1u << i)) {
                const float    w   = __shfl(cw[i], p, 16);
                const uint32_t off = (uint32_t)__shfl((int)coff[i], p, 16);
                const uint32_t pair = vb[off];
                o0 += w * b2f_lo(pair);
                o1 += w * b2f_hi(pair);
            }
        }
    }
    const uint32_t packed = (uint32_t)f2b(o0) | ((uint32_t)f2b(o1) << 16);
    reinterpret_cast<uint32_t*>(aout)[(size_t)bq * (E_DIM / 2) + head * (HDIM / 2) + l] = packed;
}

// ---------------------------------------------------------------------------
extern "C" void kernel_launch(void* const* d_in, const int* in_sizes, int n_in,
                              void* d_out, int out_size, void* d_ws, size_t ws_size,
                              hipStream_t stream) {
    const float* query     = (const float*)d_in[0];
    const float* value     = (const float*)d_in[1];
    const float* query_pos = (const float*)d_in[2];
    const float* W_off     = (const float*)d_in[3];
    const float* b_off     = (const float*)d_in[4];
    const float* W_attn    = (const float*)d_in[5];
    const float* b_attn    = (const float*)d_in[6];
    const float* W_v       = (const float*)d_in[7];
    const float* b_v       = (const float*)d_in[8];
    const float* W_out     = (const float*)d_in[9];
    const float* b_out     = (const float*)d_in[10];
    float* out = (float*)d_out;

    char* ws = (char*)d_ws;
    ushort* vbuf     = (ushort*)(ws);                  // 51200*576*2 = 58,982,400
    ushort* aout     = (ushort*)(ws + 58982400);       // 10240*576*2 = 11,796,480
    ushort* q_bf16   = (ushort*)(ws + 70778880);       // 10240*576*2 = 11,796,480
    float*  mixb     = (float*) (ws + 82575360);       // 10240*864*4 = 35,389,440
    ushort* wt_v     = (ushort*)(ws + 117964800);      // 663,552
    ushort* wt_out   = (ushort*)(ws + 118628352);      // 663,552
    ushort* wt_mix   = (ushort*)(ws + 119291904);      // 995,328
    float*  bias_mix = (float*) (ws + 120287232);      // 3,456

    prep_weights<<<(1161216 + 255) / 256, 256, 0, stream>>>(
        W_v, W_out, W_off, W_attn, b_off, b_attn, wt_v, wt_out, wt_mix, bias_mix);

    // q = query + query_pos -> bf16
    cast_add_kernel<<<(10240 * 576 / 4 + 255) / 256, 256, 0, stream>>>(
        query, query_pos, q_bf16, 10240 * 576 / 4);

    // v = value @ W_v + b_v : (51200 x 576), persistent-over-N, fused fp32 cast
    gemm_value<<<51200 / VTM, 256, 0, stream>>>(value, wt_v, b_v, vbuf);

    // mix = q @ [W_off|W_attn] + bias : (10240 x 864), fp32 out
    gemm_mfma<float><<<dim3(10240 / TM, MIXW / TN), 256, 0, stream>>>(
        q_bf16, wt_mix, bias_mix, mixb, BSZ * NQ, MIXW, E_DIM, MIXW);

    // deformable gather + softmax-weighted sum -> aout (bf16), head-major grid
    deform_kernel<<<HEADS * 640, 256, 0, stream>>>(vbuf, mixb, aout);

    // out = aout @ W_out + b_out : (10240 x 576), fp32 to d_out
    gemm_mfma<float><<<dim3(10240 / TM, E_DIM / TN), 256, 0, stream>>>(
        aout, wt_out, b_out, out, BSZ * NQ, E_DIM, E_DIM, E_DIM);
}